// Round 1
// baseline (245.746 us; speedup 1.0000x reference)
//
#include <hip/hip_runtime.h>

// GRAPE step collapse: all steps rotate about X, so the scan == one rotation by
// Theta = sum(a_k) * (DT/2).
//   out_real0 = c*r0 + s*i1    out_imag0 = c*i0 - s*r1
//   out_real1 = c*r1 + s*i0    out_imag1 = c*i1 - s*r0
// Output layout: [real0 | real1 | imag0 | imag1], each segment B floats.
//
// Pure streaming kernel: 128 MiB in + 128 MiB out.
// KEY: output is write-once/never-reread -> NON-TEMPORAL stores. This keeps the
// 134 MB input fully resident in the 256 MiB Infinity Cache across bench
// iterations (prev version's cached writes evicted ~half of it -> 65 MB/iter
// of avoidable HBM fetch) and lets the write stream go straight to DRAM like
// a memset (6.6 TB/s observed for fillBuffer vs our 2.5 TB/s mixed traffic).

typedef float f4 __attribute__((ext_vector_type(4)));

__global__ __launch_bounds__(256) void grape_kernel(
    const float* __restrict__ amps, int nsteps,
    const float* __restrict__ sreal, const float* __restrict__ simag,
    float* __restrict__ out, long long B) {
    // Theta is wave-uniform; a handful of scalar cached loads, negligible.
    float theta = 0.0f;
    for (int k = 0; k < nsteps; ++k) theta += amps[k];
    theta *= (1.0f / (float)nsteps) * 0.5f;  // DT/2 with GATE_TIME=1.0
    float c = cosf(theta);
    float s = sinf(theta);

    long long idx = (long long)blockIdx.x * blockDim.x + threadIdx.x;
    long long j = idx * 4;  // 4 columns per thread (16 B/lane per stream)

    if (j + 3 < B) {
        // main vector path (B is a multiple of 4 in practice)
        const f4 r0 = *(const f4*)(sreal + j);
        const f4 r1 = *(const f4*)(sreal + B + j);
        const f4 i0 = *(const f4*)(simag + j);
        const f4 i1 = *(const f4*)(simag + B + j);

        const f4 or0 = c * r0 + s * i1;
        const f4 or1 = c * r1 + s * i0;
        const f4 oi0 = c * i0 - s * r1;
        const f4 oi1 = c * i1 - s * r0;

        __builtin_nontemporal_store(or0, (f4*)(out + j));
        __builtin_nontemporal_store(or1, (f4*)(out + B + j));
        __builtin_nontemporal_store(oi0, (f4*)(out + 2 * B + j));
        __builtin_nontemporal_store(oi1, (f4*)(out + 3 * B + j));
    } else if (j < B) {
        // scalar tail (only if B % 4 != 0)
        for (long long t = j; t < B; ++t) {
            float r0 = sreal[t], r1 = sreal[B + t];
            float i0 = simag[t], i1 = simag[B + t];
            __builtin_nontemporal_store(c * r0 + s * i1, out + t);
            __builtin_nontemporal_store(c * r1 + s * i0, out + B + t);
            __builtin_nontemporal_store(c * i0 - s * r1, out + 2 * B + t);
            __builtin_nontemporal_store(c * i1 - s * r0, out + 3 * B + t);
        }
    }
}

extern "C" void kernel_launch(void* const* d_in, const int* in_sizes, int n_in,
                              void* d_out, int out_size, void* d_ws, size_t ws_size,
                              hipStream_t stream) {
    const float* amps  = (const float*)d_in[0];
    const float* sreal = (const float*)d_in[1];
    const float* simag = (const float*)d_in[2];
    float* out = (float*)d_out;

    int nsteps = in_sizes[0];
    long long B = (long long)in_sizes[1] / 2;  // state_real is [2, B]

    long long nthreads = (B + 3) / 4;
    int block = 256;
    long long grid = (nthreads + block - 1) / block;

    grape_kernel<<<(dim3)(unsigned)grid, block, 0, stream>>>(
        amps, nsteps, sreal, simag, out, B);
}

// Round 2
// 244.052 us; speedup vs baseline: 1.0069x; 1.0069x over previous
//
#include <hip/hip_runtime.h>

// GRAPE step collapse: all steps rotate about X, so the scan == one rotation by
// Theta = sum(a_k) * (DT/2).
//   out_real0 = c*r0 + s*i1    out_imag0 = c*i0 - s*r1
//   out_real1 = c*r1 + s*i0    out_imag1 = c*i1 - s*r0
// Output layout: [real0 | real1 | imag0 | imag1], each segment B floats.
//
// Pure streaming kernel: 128 MiB in + 128 MiB out. Memory-bound.
// R1 lesson: nt stores = -6us (reverted), FETCH/WRITE unmoved by nt hint.
// R2 change: persistent grid-stride (2048 blocks = 32 waves/CU exactly resident,
// G11) instead of 8192 one-shot blocks (wave churn, OccupancyPercent 67%).
// 8 floats/thread/stream per iteration -> 8 independent 16B loads in flight.

typedef float f4 __attribute__((ext_vector_type(4)));

__global__ __launch_bounds__(256) void grape_kernel(
    const float* __restrict__ amps, int nsteps,
    const float* __restrict__ sreal, const float* __restrict__ simag,
    float* __restrict__ out, long long B) {
    // Theta is wave-uniform; a handful of scalar cached loads, negligible.
    float theta = 0.0f;
    for (int k = 0; k < nsteps; ++k) theta += amps[k];
    theta *= (1.0f / (float)nsteps) * 0.5f;  // DT/2 with GATE_TIME=1.0
    const float c = cosf(theta);
    const float s = sinf(theta);

    const long long nv = B >> 3;  // number of 8-float chunks per stream
    const long long stride = (long long)gridDim.x * blockDim.x;

    for (long long v = (long long)blockIdx.x * blockDim.x + threadIdx.x;
         v < nv; v += stride) {
        const long long j = v << 3;

        const f4 r0a = *(const f4*)(sreal + j);
        const f4 r0b = *(const f4*)(sreal + j + 4);
        const f4 r1a = *(const f4*)(sreal + B + j);
        const f4 r1b = *(const f4*)(sreal + B + j + 4);
        const f4 i0a = *(const f4*)(simag + j);
        const f4 i0b = *(const f4*)(simag + j + 4);
        const f4 i1a = *(const f4*)(simag + B + j);
        const f4 i1b = *(const f4*)(simag + B + j + 4);

        *(f4*)(out + j)             = c * r0a + s * i1a;
        *(f4*)(out + j + 4)         = c * r0b + s * i1b;
        *(f4*)(out + B + j)         = c * r1a + s * i0a;
        *(f4*)(out + B + j + 4)     = c * r1b + s * i0b;
        *(f4*)(out + 2 * B + j)     = c * i0a - s * r1a;
        *(f4*)(out + 2 * B + j + 4) = c * i0b - s * r1b;
        *(f4*)(out + 3 * B + j)     = c * i1a - s * r0a;
        *(f4*)(out + 3 * B + j + 4) = c * i1b - s * r0b;
    }

    // scalar tail (only if B % 8 != 0)
    const long long tail_start = nv << 3;
    const long long t =
        tail_start + (long long)blockIdx.x * blockDim.x + threadIdx.x;
    if (t < B) {
        const float r0 = sreal[t], r1 = sreal[B + t];
        const float i0 = simag[t], i1 = simag[B + t];
        out[t]         = c * r0 + s * i1;
        out[B + t]     = c * r1 + s * i0;
        out[2 * B + t] = c * i0 - s * r1;
        out[3 * B + t] = c * i1 - s * r0;
    }
}

extern "C" void kernel_launch(void* const* d_in, const int* in_sizes, int n_in,
                              void* d_out, int out_size, void* d_ws, size_t ws_size,
                              hipStream_t stream) {
    const float* amps  = (const float*)d_in[0];
    const float* sreal = (const float*)d_in[1];
    const float* simag = (const float*)d_in[2];
    float* out = (float*)d_out;

    int nsteps = in_sizes[0];
    long long B = (long long)in_sizes[1] / 2;  // state_real is [2, B]

    const int block = 256;
    long long nv = B >> 3;
    long long grid = (nv + block - 1) / block;
    if (grid > 2048) grid = 2048;  // persistent: 2048*256 thr = 32 waves/CU
    if (grid < 1) grid = 1;

    grape_kernel<<<(dim3)(unsigned)grid, block, 0, stream>>>(
        amps, nsteps, sreal, simag, out, B);
}

// Round 3
// 240.190 us; speedup vs baseline: 1.0231x; 1.0161x over previous
//
#include <hip/hip_runtime.h>

// GRAPE step collapse: all steps rotate about X, so the scan == one rotation by
// Theta = sum(a_k) * (DT/2).
//   out_real0 = c*r0 + s*i1    out_imag0 = c*i0 - s*r1
//   out_real1 = c*r1 + s*i0    out_imag1 = c*i1 - s*r0
// Output layout: [real0 | real1 | imag0 | imag1], each segment B floats.
//
// R3 structure: the rotation couples segments only in PAIRS:
//   pair h=0: (r0, i1) -> (out0, out3)
//   pair h=1: (r1, i0) -> (out1, out2)
// so split the grid into two independent halves, each a pure 2-load/2-store
// stream (copy-like; m13's float4 copy hits 6.29 TB/s with 1+1 streams).
// This halves the per-wave vmcnt fan-in (wave waited on 4 distant lines
// before any store; now 2) after R0-R2 showed dur pinned at 81-87us across
// one-shot/persistent/nt variants (structure-insensitive 2.4 TB/s).
//   x = sreal + h*B, y = simag + (1-h)*B
//   out_r = c*x + s*y -> out + h*B
//   out_i = c*y - s*x -> out + (3-h)*B

typedef float f4 __attribute__((ext_vector_type(4)));

__global__ __launch_bounds__(256) void grape_kernel(
    const float* __restrict__ amps, int nsteps,
    const float* __restrict__ sreal, const float* __restrict__ simag,
    float* __restrict__ out, long long B, long long blocks_per_half) {
    // Theta is wave-uniform; a handful of scalar cached loads, negligible.
    float theta = 0.0f;
    for (int k = 0; k < nsteps; ++k) theta += amps[k];
    theta *= (1.0f / (float)nsteps) * 0.5f;  // DT/2 with GATE_TIME=1.0
    const float c = cosf(theta);
    const float s = sinf(theta);

    const long long h = (blockIdx.x >= blocks_per_half) ? 1 : 0;
    const long long v = ((long long)blockIdx.x - h * blocks_per_half) * blockDim.x
                        + threadIdx.x;
    const long long j = v * 4;

    const float* __restrict__ x = sreal + h * B;        // r0 or r1
    const float* __restrict__ y = simag + (1 - h) * B;  // i1 or i0
    float* __restrict__ outr = out + h * B;             // out0 or out1
    float* __restrict__ outi = out + (3 - h) * B;       // out3 or out2

    if (j + 3 < B) {
        const f4 xv = *(const f4*)(x + j);
        const f4 yv = *(const f4*)(y + j);
        *(f4*)(outr + j) = c * xv + s * yv;
        *(f4*)(outi + j) = c * yv - s * xv;
    } else if (j < B) {
        for (long long t = j; t < B; ++t) {
            const float xs = x[t], ys = y[t];
            outr[t] = c * xs + s * ys;
            outi[t] = c * ys - s * xs;
        }
    }
}

extern "C" void kernel_launch(void* const* d_in, const int* in_sizes, int n_in,
                              void* d_out, int out_size, void* d_ws, size_t ws_size,
                              hipStream_t stream) {
    const float* amps  = (const float*)d_in[0];
    const float* sreal = (const float*)d_in[1];
    const float* simag = (const float*)d_in[2];
    float* out = (float*)d_out;

    int nsteps = in_sizes[0];
    long long B = (long long)in_sizes[1] / 2;  // state_real is [2, B]

    const int block = 256;
    long long nv = (B + 3) / 4;                       // f4 chunks per half
    long long blocks_per_half = (nv + block - 1) / block;
    long long grid = 2 * blocks_per_half;             // one-shot (R0 > R2)

    grape_kernel<<<(dim3)(unsigned)grid, block, 0, stream>>>(
        amps, nsteps, sreal, simag, out, B, blocks_per_half);
}